// Round 4
// baseline (448.370 us; speedup 1.0000x reference)
//
#include <hip/hip_runtime.h>
#include <hip/hip_bf16.h>

#define D_MODEL 2048
#define SEQ     2048
#define BATCH   2
#define NH      16
#define HD      128
#define MROWS   (BATCH*SEQ)   // 4096

typedef __attribute__((ext_vector_type(8)))  short bf16x8;
typedef __attribute__((ext_vector_type(4)))  float f32x4;
typedef __attribute__((ext_vector_type(16))) float f32x16;
typedef __attribute__((ext_vector_type(4)))  unsigned int u32x4;

// async global->LDS, 16B per lane. LDS dest is wave-uniform base + lane*16 (implicit).
static __device__ __forceinline__ void lds16(const void* g, void* l) {
    __builtin_amdgcn_global_load_lds(
        (const __attribute__((address_space(1))) void*)g,
        (__attribute__((address_space(3))) void*)l,
        16, 0, 0);
}

static __device__ __forceinline__ unsigned int pk2(float a, float b) {
    const unsigned int lo = __bfloat16_as_ushort(__float2bfloat16(a));
    const unsigned int hh = __bfloat16_as_ushort(__float2bfloat16(b));
    return lo | (hh << 16);
}

// ---------------- all f32->bf16 conversions in one launch ----------------
// segs: 3 activations (8192 blocks each), 4 weights (4096 blocks each)
__global__ __launch_bounds__(256) void cvt_all(
    const float* __restrict__ q,  const float* __restrict__ k,  const float* __restrict__ v,
    const float* __restrict__ wq, const float* __restrict__ wk, const float* __restrict__ wv,
    const float* __restrict__ wo,
    unsigned short* __restrict__ qb, unsigned short* __restrict__ kb, unsigned short* __restrict__ vb,
    unsigned short* __restrict__ wqb, unsigned short* __restrict__ wkb,
    unsigned short* __restrict__ wvb, unsigned short* __restrict__ wob)
{
    const int b = blockIdx.x;
    const float* src; unsigned short* dst; int idx;
    if (b < 24576) {
        const int s = b >> 13;
        idx = (b & 8191)*256 + threadIdx.x;
        src = (s==0) ? q : (s==1) ? k : v;
        dst = (s==0) ? qb : (s==1) ? kb : vb;
    } else {
        const int bb = b - 24576;
        const int s = bb >> 12;
        idx = (bb & 4095)*256 + threadIdx.x;
        src = (s==0) ? wq : (s==1) ? wk : (s==2) ? wv : wo;
        dst = (s==0) ? wqb : (s==1) ? wkb : (s==2) ? wvb : wob;
    }
    const float4 a = ((const float4*)src)[idx];
    ushort4 o;
    o.x = __bfloat16_as_ushort(__float2bfloat16(a.x));
    o.y = __bfloat16_as_ushort(__float2bfloat16(a.y));
    o.z = __bfloat16_as_ushort(__float2bfloat16(a.z));
    o.w = __bfloat16_as_ushort(__float2bfloat16(a.w));
    ((ushort4*)dst)[idx] = o;
}

// ---------------- GEMM: C = A·W^T + bias, 128x128 tile, BK=32 ----------------
// 4-deep LDS pipeline (stage t+2 while computing t), counted vmcnt(4), raw barriers.
template <typename OutT>
__global__ __launch_bounds__(256, 2) void gemm_bt_bias(
    const __hip_bfloat16* __restrict__ A,
    const __hip_bfloat16* __restrict__ W,
    const float* __restrict__ bias,
    OutT* __restrict__ C,
    const int M, const int N, const int K)
{
    __shared__ __hip_bfloat16 As[4][128*32];   // 4 buffers x 8KB
    __shared__ __hip_bfloat16 Bs[4][128*32];
    const int nb   = N >> 7;
    const int bm   = blockIdx.x / nb;
    const int bn   = blockIdx.x % nb;
    const int tid  = threadIdx.x;
    const int lane = tid & 63;
    const int w    = tid >> 6;
    const int wr   = (w >> 1) * 64;
    const int wc   = (w & 1) * 64;
    const int l15  = lane & 15, l4 = lane >> 4;

    const int srow = w*32 + (lane>>2);
    const __hip_bfloat16* ga = A + (size_t)(bm*128 + srow)*K + (lane&3)*8;
    const __hip_bfloat16* gb = W + (size_t)(bn*128 + srow)*K + (lane&3)*8;

#define GSTAGE(Q_, KT_) do {                                          \
        lds16(ga + (KT_),                &As[Q_][(w*32)*32]);         \
        lds16(ga + (KT_) + (size_t)16*K, &As[Q_][(w*32+16)*32]);      \
        lds16(gb + (KT_),                &Bs[Q_][(w*32)*32]);         \
        lds16(gb + (KT_) + (size_t)16*K, &Bs[Q_][(w*32+16)*32]);      \
    } while (0)

    f32x4 acc[4][4] = {};
    const int NT = K >> 5;

    GSTAGE(0, 0);
    GSTAGE(1, 32);
    asm volatile("s_waitcnt vmcnt(4)" ::: "memory");   // stage(0) landed
    __builtin_amdgcn_s_barrier();

    for (int t = 0; t < NT; ++t) {
        const int q = t & 3;
        if (t + 2 < NT) GSTAGE((t+2)&3, (t+2)*32);     // WAR-safe: buf read ended 2 barriers ago
        bf16x8 af[4], bfr[4];
        #pragma unroll
        for (int i = 0; i < 4; i++) {
            af[i]  = *(const bf16x8*)&As[q][(wr + i*16 + l15)*32 + l4*8];
            bfr[i] = *(const bf16x8*)&Bs[q][(wc + i*16 + l15)*32 + l4*8];
        }
        __builtin_amdgcn_s_setprio(1);
        #pragma unroll
        for (int i = 0; i < 4; i++)
            #pragma unroll
            for (int j = 0; j < 4; j++)
                acc[i][j] = __builtin_amdgcn_mfma_f32_16x16x32_bf16(af[i], bfr[j], acc[i][j], 0, 0, 0);
        __builtin_amdgcn_s_setprio(0);
        if (t + 2 < NT) {
            asm volatile("s_waitcnt vmcnt(4)" ::: "memory");  // stage(t+1) landed, t+2 in flight
            __builtin_amdgcn_s_barrier();
        } else if (t + 1 < NT) {
            asm volatile("s_waitcnt vmcnt(0)" ::: "memory");  // tail: drain last stage
            __builtin_amdgcn_s_barrier();
        }
    }
#undef GSTAGE

    float bv[4];
    #pragma unroll
    for (int j = 0; j < 4; j++)
        bv[j] = bias[bn*128 + wc + j*16 + l15];
    #pragma unroll
    for (int i = 0; i < 4; i++) {
        #pragma unroll
        for (int j = 0; j < 4; j++) {
            const int col = bn*128 + wc + j*16 + l15;
            #pragma unroll
            for (int r = 0; r < 4; r++) {
                const int row = bm*128 + wr + i*16 + l4*4 + r;
                const float v = acc[i][j][r] + bv[j];
                if constexpr (sizeof(OutT) == 2)
                    C[(size_t)row*N + col] = OutT(__float2bfloat16(v));
                else
                    C[(size_t)row*N + col] = OutT(v);
            }
        }
    }
}

// sincos table: tab[s*256 + d] = cos(s*invf[d]), tab[s*256+128+d] = sin(...)
__global__ __launch_bounds__(256) void rope_table(float* __restrict__ tab)
{
    const int i = blockIdx.x*256 + threadIdx.x;
    const int s = i >> 7, d = i & 127;
    const float invf = expf(-(float)d * (9.210340371976184f / 1024.0f));
    const float f = (float)s * invf;
    tab[(size_t)s*256 + d]       = cosf(f);
    tab[(size_t)s*256 + 128 + d] = sinf(f);
}

// interleaved-rotate_half RoPE, in place, Q then K in one launch.
__global__ __launch_bounds__(256) void rope_apply_qk(
    __hip_bfloat16* __restrict__ Qp, __hip_bfloat16* __restrict__ Kp,
    const float* __restrict__ tab)
{
    const int tid  = threadIdx.x;
    const int w    = tid >> 6, lane = tid & 63;
    int rowid = blockIdx.x*4 + w;                 // 0..131071
    __hip_bfloat16* X = Qp;
    if (rowid >= BATCH*SEQ*NH) { X = Kp; rowid -= BATCH*SEQ*NH; }
    const int h  = rowid & 15;
    const int bs = rowid >> 4;
    const int s  = bs & (SEQ-1);
    __hip_bfloat16* base = X + (size_t)bs*D_MODEL + h*HD;
    const float v0 = __bfloat162float(base[lane]);
    const float v1 = __bfloat162float(base[lane+64]);
    const float* tc = tab + (size_t)s*256;
    const float c0 = tc[lane],    sn0 = tc[128+lane];
    const float c1 = tc[64+lane], sn1 = tc[192+lane];
    const float a0 = __shfl(v0, (2*lane+1) & 63);
    const float a1 = __shfl(v1, (2*lane+1) & 63);
    const float pA = (lane >= 32) ? a1 : a0;
    const float b0 = __shfl(v0, (2*lane) & 63);
    const float b1 = __shfl(v1, (2*lane) & 63);
    const float pB = (lane >= 32) ? b1 : b0;
    base[lane]    = __float2bfloat16(v0*c0 - pA*sn0);
    base[lane+64] = __float2bfloat16(v1*c1 + pB*sn1);
}

// V [B*S][D_MODEL] -> Vt [B*H][HD][SEQ]  (per-head transpose)
__global__ __launch_bounds__(256) void transpose_v(
    const unsigned short* __restrict__ V,
    unsigned short* __restrict__ Vt)
{
    __shared__ unsigned short t[64][66];
    const int bid = blockIdx.x;
    const int st = bid & 31;
    const int dt = (bid >> 5) & 1;
    const int bh = bid >> 6;
    const int b  = bh >> 4, h = bh & 15;
    const int tid = threadIdx.x;
    const int r = tid >> 5;
    const int c = tid & 31;
    #pragma unroll
    for (int i = 0; i < 8; i++) {
        const int row = i*8 + r;
        const unsigned int v = *(const unsigned int*)(
            V + (size_t)(b*SEQ + st*64 + row)*D_MODEL + h*HD + dt*64 + c*2);
        t[row][c*2]   = (unsigned short)(v & 0xffffu);
        t[row][c*2+1] = (unsigned short)(v >> 16);
    }
    __syncthreads();
    #pragma unroll
    for (int i = 0; i < 8; i++) {
        const int drow = i*8 + r;
        const unsigned int pk = (unsigned int)t[c*2][drow] | ((unsigned int)t[c*2+1][drow] << 16);
        *(unsigned int*)(Vt + ((size_t)bh*HD + dt*64 + drow)*SEQ + st*64 + c*2) = pk;
    }
}

// ---------------------------------------------------------------------------
// Flash attention: 2-wave blocks (64 q rows), KV chunk 32, 32x32x16 MFMA,
// swapped QK^T, exp2-domain in-register softmax, swizzled LDS K/V, dbuf.
// ---------------------------------------------------------------------------
__global__ __launch_bounds__(128) void flash_attn(
    const __hip_bfloat16* __restrict__ Qg,
    const __hip_bfloat16* __restrict__ Kg,
    const __hip_bfloat16* __restrict__ Vtg,
    __hip_bfloat16* __restrict__ ctx)
{
    __shared__ __hip_bfloat16 Ks[2][32*128];   // 16 KB
    __shared__ __hip_bfloat16 Vs[2][128*32];   // 16 KB

    const int tid  = threadIdx.x;
    const int w    = tid >> 6;           // wave 0..1
    const int lane = tid & 63;
    const int l31  = lane & 31;
    const int hi   = lane >> 5;
    const bool hib = (hi != 0);

    const int bid0 = blockIdx.x;                   // 1024 blocks
    const int bid  = (bid0 & 7)*128 + (bid0 >> 3); // XCD-aware swizzle (bijective)
    const int bh   = bid >> 5;                     // 0..31
    const int qt   = bid & 31;
    const int bi   = bh >> 4, h = bh & 15;
    const int q0   = qt*64 + w*32;

    const float SC2 = 0.12751745f;   // log2(e)/sqrt(128)

    bf16x8 aq[8];
    {
        const __hip_bfloat16* qp =
            Qg + (size_t)(bi*SEQ + q0 + l31)*D_MODEL + h*HD + hi*8;
        #pragma unroll
        for (int ds = 0; ds < 8; ds++) aq[ds] = *(const bf16x8*)(qp + ds*16);
    }

    const __hip_bfloat16* kbase = Kg  + (size_t)(bi*SEQ)*D_MODEL + h*HD;
    const __hip_bfloat16* vbase = Vtg + (size_t)bh*HD*SEQ;

#define STAGE(NB, KV) do {                                                          \
        _Pragma("unroll")                                                           \
        for (int i_ = 0; i_ < 4; i_++) {                                            \
            const int kr_ = w*16 + i_*4 + (lane>>4);                                \
            lds16(kbase + (size_t)((KV) + kr_)*D_MODEL + (((lane&15) ^ (kr_&15))*8),\
                  &Ks[NB][(w*16 + i_*4)*128]);                                      \
        }                                                                           \
        _Pragma("unroll")                                                           \
        for (int i_ = 0; i_ < 4; i_++) {                                            \
            const int vr_ = w*64 + i_*16 + (lane>>2);                               \
            lds16(vbase + (size_t)vr_*SEQ + (KV) + (((lane&3) ^ (vr_&3))*8),        \
                  &Vs[NB][(w*64 + i_*16)*32]);                                      \
        }                                                                           \
    } while (0)

    f32x16 o0 = {}, o1 = {}, o2 = {}, o3 = {};
    float ms = -1e30f, l_run = 0.0f;

    STAGE(0, 0);

    for (int t = 0; t < SEQ/32; t++) {
        const int cb = t & 1;
        __syncthreads();                          // drains vmcnt: stage(t) visible
        if (t < SEQ/32 - 1) STAGE(cb^1, (t+1)*32);

        // ---- QK^T (swapped): S^T = mfma(A=K rows, B=Q rows) ----
        f32x16 p = {};
        __builtin_amdgcn_s_setprio(1);
        #pragma unroll
        for (int ds = 0; ds < 8; ds++) {
            const int sl = ((ds*2 + hi) ^ (l31 & 15)) * 8;
            const bf16x8 kf = *(const bf16x8*)&Ks[cb][l31*128 + sl];
            p = __builtin_amdgcn_mfma_f32_32x32x16_bf16(kf, aq[ds], p, 0, 0, 0);
        }
        __builtin_amdgcn_s_setprio(0);

        // ---- online softmax in exp2 domain ----
        float pm = p[0];
        #pragma unroll
        for (int r = 1; r < 16; r++) pm = fmaxf(pm, p[r]);
        pm = fmaxf(pm, __shfl_xor(pm, 32));
        const float pms = pm * SC2;

        if (!__all(pms <= ms + 11.541560f)) {     // defer-max, THR=8 nats
            const float msn = fmaxf(ms, pms);
            const float al = __builtin_amdgcn_exp2f(ms - msn);
            l_run *= al;
            ms = msn;
            float alr[16];
            #pragma unroll
            for (int r = 0; r < 16; r++)
                alr[r] = __shfl(al, (r&3) + 8*(r>>2) + (hib ? 4 : 0));
            #pragma unroll
            for (int r = 0; r < 16; r++) {
                o0[r] *= alr[r]; o1[r] *= alr[r]; o2[r] *= alr[r]; o3[r] *= alr[r];
            }
        }

        #pragma unroll
        for (int r = 0; r < 16; r++)
            p[r] = __builtin_amdgcn_exp2f(__builtin_fmaf(p[r], SC2, -ms));
        float rs = 0.0f;
        #pragma unroll
        for (int r = 0; r < 16; r++) rs += p[r];
        rs += __shfl_xor(rs, 32);
        l_run += rs;

        // ---- PV: O += P·V ----
        __builtin_amdgcn_s_setprio(1);
#define PV_STEP(KS) do {                                                            \
            const unsigned int A0_ = pk2(p[8*(KS)+0], p[8*(KS)+1]);                 \
            const unsigned int A1_ = pk2(p[8*(KS)+2], p[8*(KS)+3]);                 \
            const unsigned int B0_ = pk2(p[8*(KS)+4], p[8*(KS)+5]);                 \
            const unsigned int B1_ = pk2(p[8*(KS)+6], p[8*(KS)+7]);                 \
            const unsigned int s0_ = hib ? A0_ : B0_;                               \
            const unsigned int s1_ = hib ? A1_ : B1_;                               \
            const unsigned int r0_ = (unsigned int)__shfl_xor((int)s0_, 32);        \
            const unsigned int r1_ = (unsigned int)__shfl_xor((int)s1_, 32);        \
            u32x4 au_;                                                              \
            au_.x = hib ? r0_ : A0_;  au_.y = hib ? r1_ : A1_;                      \
            au_.z = hib ? B0_ : r0_;  au_.w = hib ? B1_ : r1_;                      \
            const bf16x8 pa_ = *(const bf16x8*)&au_;                                \
            const int ko_ = (((KS)*2 + hi) ^ (l31 & 3)) * 8;                        \
            o0 = __builtin_amdgcn_mfma_f32_32x32x16_bf16(pa_,                       \
                     *(const bf16x8*)&Vs[cb][(  0 + l31)*32 + ko_], o0, 0, 0, 0);   \
            o1 = __builtin_amdgcn_mfma_f32_32x32x16_bf16(pa_,                       \
                     *(const bf16x8*)&Vs[cb][( 32 + l31)*32 + ko_], o1, 0, 0, 0);   \
            o2 = __builtin_amdgcn_mfma_f32_32x32x16_bf16(pa_,                       \
                     *(const bf16x8*)&Vs[cb][( 64 + l31)*32 + ko_], o2, 0, 0, 0);   \
            o3 = __builtin_amdgcn_mfma_f32_32x32x16_bf16(pa_,                       \
                     *(const bf16x8*)&Vs[cb][( 96 + l31)*32 + ko_], o3, 0, 0, 0);   \
        } while (0)
        PV_STEP(0); PV_STEP(1);
#undef PV_STEP
        __builtin_amdgcn_s_setprio(0);
    }

    const float inv = 1.0f / l_run;
    float invr[16];
    #pragma unroll
    for (int r = 0; r < 16; r++)
        invr[r] = __shfl(inv, (r&3) + 8*(r>>2) + (hib ? 4 : 0));

    #pragma unroll
    for (int r = 0; r < 16; r++) {
        const int qr = q0 + (r&3) + 8*(r>>2) + (hib ? 4 : 0);
        __hip_bfloat16* cp = ctx + (size_t)(bi*SEQ + qr)*D_MODEL + h*HD + l31;
        cp[0]  = __float2bfloat16(o0[r] * invr[r]);
        cp[32] = __float2bfloat16(o1[r] * invr[r]);
        cp[64] = __float2bfloat16(o2[r] * invr[r]);
        cp[96] = __float2bfloat16(o3[r] * invr[r]);
    }
#undef STAGE
}

extern "C" void kernel_launch(void* const* d_in, const int* in_sizes, int n_in,
                              void* d_out, int out_size, void* d_ws, size_t ws_size,
                              hipStream_t stream)
{
    const float* query = (const float*)d_in[0];
    const float* key   = (const float*)d_in[1];
    const float* value = (const float*)d_in[2];
    const float* Wq    = (const float*)d_in[3];
    const float* bq    = (const float*)d_in[4];
    const float* Wk    = (const float*)d_in[5];
    const float* bk    = (const float*)d_in[6];
    const float* Wv    = (const float*)d_in[7];
    const float* bv    = (const float*)d_in[8];
    const float* Wo    = (const float*)d_in[9];
    const float* bo    = (const float*)d_in[10];
    float* out = (float*)d_out;

    char* ws = (char*)d_ws;
    const size_t MB = 1024*1024;
    __hip_bfloat16* qb  = (__hip_bfloat16*)(ws);
    __hip_bfloat16* kbuf= (__hip_bfloat16*)(ws + 16*MB);
    __hip_bfloat16* vbuf= (__hip_bfloat16*)(ws + 32*MB);
    __hip_bfloat16* Qp  = (__hip_bfloat16*)(ws + 48*MB);
    __hip_bfloat16* Kp  = (__hip_bfloat16*)(ws + 64*MB);
    __hip_bfloat16* Vp  = (__hip_bfloat16*)(ws + 80*MB);
    __hip_bfloat16* Vt  = (__hip_bfloat16*)(ws + 96*MB);
    __hip_bfloat16* ctx = (__hip_bfloat16*)(ws + 112*MB);
    __hip_bfloat16* Wqb = (__hip_bfloat16*)(ws + 128*MB);
    __hip_bfloat16* Wkb = (__hip_bfloat16*)(ws + 136*MB);
    __hip_bfloat16* Wvb = (__hip_bfloat16*)(ws + 144*MB);
    __hip_bfloat16* Wob = (__hip_bfloat16*)(ws + 152*MB);
    float*          tab = (float*)         (ws + 160*MB);

    cvt_all<<<40960, 256, 0, stream>>>(query, key, value, Wq, Wk, Wv, Wo,
        (unsigned short*)qb, (unsigned short*)kbuf, (unsigned short*)vbuf,
        (unsigned short*)Wqb, (unsigned short*)Wkb, (unsigned short*)Wvb,
        (unsigned short*)Wob);

    rope_table<<<SEQ*HD/256, 256, 0, stream>>>(tab);

    const int gemm_grid = (MROWS/128)*(D_MODEL/128);
    gemm_bt_bias<__hip_bfloat16><<<gemm_grid, 256, 0, stream>>>(qb,   Wqb, bq, Qp, MROWS, D_MODEL, D_MODEL);
    gemm_bt_bias<__hip_bfloat16><<<gemm_grid, 256, 0, stream>>>(kbuf, Wkb, bk, Kp, MROWS, D_MODEL, D_MODEL);
    gemm_bt_bias<__hip_bfloat16><<<gemm_grid, 256, 0, stream>>>(vbuf, Wvb, bv, Vp, MROWS, D_MODEL, D_MODEL);

    rope_apply_qk<<<2*BATCH*SEQ*NH/4, 256, 0, stream>>>(Qp, Kp, tab);
    transpose_v<<<BATCH*NH*2*(SEQ/64), 256, 0, stream>>>((const unsigned short*)Vp, (unsigned short*)Vt);

    flash_attn<<<BATCH*NH*(SEQ/64), 128, 0, stream>>>(Qp, Kp, Vt, ctx);

    gemm_bt_bias<float><<<gemm_grid, 256, 0, stream>>>(ctx, Wob, bo, out, MROWS, D_MODEL, D_MODEL);
}

// Round 5
// 397.911 us; speedup vs baseline: 1.1268x; 1.1268x over previous
//
#include <hip/hip_runtime.h>
#include <hip/hip_bf16.h>

#define D_MODEL 2048
#define SEQ     2048
#define BATCH   2
#define NH      16
#define HD      128
#define MROWS   (BATCH*SEQ)   // 4096

typedef __attribute__((ext_vector_type(8)))  short bf16x8;
typedef __attribute__((ext_vector_type(4)))  float f32x4;
typedef __attribute__((ext_vector_type(16))) float f32x16;
typedef __attribute__((ext_vector_type(4)))  unsigned int u32x4;

// async global->LDS, 16B per lane. LDS dest is wave-uniform base + lane*16 (implicit).
static __device__ __forceinline__ void lds16(const void* g, void* l) {
    __builtin_amdgcn_global_load_lds(
        (const __attribute__((address_space(1))) void*)g,
        (__attribute__((address_space(3))) void*)l,
        16, 0, 0);
}

static __device__ __forceinline__ unsigned int pk2(float a, float b) {
    const unsigned int lo = __bfloat16_as_ushort(__float2bfloat16(a));
    const unsigned int hh = __bfloat16_as_ushort(__float2bfloat16(b));
    return lo | (hh << 16);
}

// ---------------- all f32->bf16 conversions in one launch ----------------
__global__ __launch_bounds__(256) void cvt_all(
    const float* __restrict__ q,  const float* __restrict__ k,  const float* __restrict__ v,
    const float* __restrict__ wq, const float* __restrict__ wk, const float* __restrict__ wv,
    const float* __restrict__ wo,
    unsigned short* __restrict__ qb, unsigned short* __restrict__ kb, unsigned short* __restrict__ vb,
    unsigned short* __restrict__ wqb, unsigned short* __restrict__ wkb,
    unsigned short* __restrict__ wvb, unsigned short* __restrict__ wob)
{
    const int b = blockIdx.x;
    const float* src; unsigned short* dst; int idx;
    if (b < 24576) {
        const int s = b >> 13;
        idx = (b & 8191)*256 + threadIdx.x;
        src = (s==0) ? q : (s==1) ? k : v;
        dst = (s==0) ? qb : (s==1) ? kb : vb;
    } else {
        const int bb = b - 24576;
        const int s = bb >> 12;
        idx = (bb & 4095)*256 + threadIdx.x;
        src = (s==0) ? wq : (s==1) ? wk : (s==2) ? wv : wo;
        dst = (s==0) ? wqb : (s==1) ? wkb : (s==2) ? wvb : wob;
    }
    const float4 a = ((const float4*)src)[idx];
    ushort4 o;
    o.x = __bfloat16_as_ushort(__float2bfloat16(a.x));
    o.y = __bfloat16_as_ushort(__float2bfloat16(a.y));
    o.z = __bfloat16_as_ushort(__float2bfloat16(a.z));
    o.w = __bfloat16_as_ushort(__float2bfloat16(a.w));
    ((ushort4*)dst)[idx] = o;
}

// ---------------- GEMM: C = A·W^T + bias, 128x128 tile, BK=32 ----------------
// 4-deep LDS pipeline (stage t+2 while computing t), counted vmcnt(4), raw barriers.
template <typename OutT>
__global__ __launch_bounds__(256, 2) void gemm_bt_bias(
    const __hip_bfloat16* __restrict__ A,
    const __hip_bfloat16* __restrict__ W,
    const float* __restrict__ bias,
    OutT* __restrict__ C,
    const int M, const int N, const int K)
{
    __shared__ __hip_bfloat16 As[4][128*32];
    __shared__ __hip_bfloat16 Bs[4][128*32];
    const int nb   = N >> 7;
    const int bm   = blockIdx.x / nb;
    const int bn   = blockIdx.x % nb;
    const int tid  = threadIdx.x;
    const int lane = tid & 63;
    const int w    = tid >> 6;
    const int wr   = (w >> 1) * 64;
    const int wc   = (w & 1) * 64;
    const int l15  = lane & 15, l4 = lane >> 4;

    const int srow = w*32 + (lane>>2);
    const __hip_bfloat16* ga = A + (size_t)(bm*128 + srow)*K + (lane&3)*8;
    const __hip_bfloat16* gb = W + (size_t)(bn*128 + srow)*K + (lane&3)*8;

#define GSTAGE(Q_, KT_) do {                                          \
        lds16(ga + (KT_),                &As[Q_][(w*32)*32]);         \
        lds16(ga + (KT_) + (size_t)16*K, &As[Q_][(w*32+16)*32]);      \
        lds16(gb + (KT_),                &Bs[Q_][(w*32)*32]);         \
        lds16(gb + (KT_) + (size_t)16*K, &Bs[Q_][(w*32+16)*32]);      \
    } while (0)

    f32x4 acc[4][4] = {};
    const int NT = K >> 5;

    GSTAGE(0, 0);
    GSTAGE(1, 32);
    asm volatile("s_waitcnt vmcnt(4)" ::: "memory");
    __builtin_amdgcn_s_barrier();

    for (int t = 0; t < NT; ++t) {
        const int q = t & 3;
        if (t + 2 < NT) GSTAGE((t+2)&3, (t+2)*32);
        bf16x8 af[4], bfr[4];
        #pragma unroll
        for (int i = 0; i < 4; i++) {
            af[i]  = *(const bf16x8*)&As[q][(wr + i*16 + l15)*32 + l4*8];
            bfr[i] = *(const bf16x8*)&Bs[q][(wc + i*16 + l15)*32 + l4*8];
        }
        __builtin_amdgcn_s_setprio(1);
        #pragma unroll
        for (int i = 0; i < 4; i++)
            #pragma unroll
            for (int j = 0; j < 4; j++)
                acc[i][j] = __builtin_amdgcn_mfma_f32_16x16x32_bf16(af[i], bfr[j], acc[i][j], 0, 0, 0);
        __builtin_amdgcn_s_setprio(0);
        if (t + 2 < NT) {
            asm volatile("s_waitcnt vmcnt(4)" ::: "memory");
            __builtin_amdgcn_s_barrier();
        } else if (t + 1 < NT) {
            asm volatile("s_waitcnt vmcnt(0)" ::: "memory");
            __builtin_amdgcn_s_barrier();
        }
    }
#undef GSTAGE

    float bv[4];
    #pragma unroll
    for (int j = 0; j < 4; j++)
        bv[j] = bias[bn*128 + wc + j*16 + l15];
    #pragma unroll
    for (int i = 0; i < 4; i++) {
        #pragma unroll
        for (int j = 0; j < 4; j++) {
            const int col = bn*128 + wc + j*16 + l15;
            #pragma unroll
            for (int r = 0; r < 4; r++) {
                const int row = bm*128 + wr + i*16 + l4*4 + r;
                const float v = acc[i][j][r] + bv[j];
                if constexpr (sizeof(OutT) == 2)
                    C[(size_t)row*N + col] = OutT(__float2bfloat16(v));
                else
                    C[(size_t)row*N + col] = OutT(v);
            }
        }
    }
}

// sincos table
__global__ __launch_bounds__(256) void rope_table(float* __restrict__ tab)
{
    const int i = blockIdx.x*256 + threadIdx.x;
    const int s = i >> 7, d = i & 127;
    const float invf = expf(-(float)d * (9.210340371976184f / 1024.0f));
    const float f = (float)s * invf;
    tab[(size_t)s*256 + d]       = cosf(f);
    tab[(size_t)s*256 + 128 + d] = sinf(f);
}

// interleaved-rotate_half RoPE, in place, Q then K in one launch.
__global__ __launch_bounds__(256) void rope_apply_qk(
    __hip_bfloat16* __restrict__ Qp, __hip_bfloat16* __restrict__ Kp,
    const float* __restrict__ tab)
{
    const int tid  = threadIdx.x;
    const int w    = tid >> 6, lane = tid & 63;
    int rowid = blockIdx.x*4 + w;
    __hip_bfloat16* X = Qp;
    if (rowid >= BATCH*SEQ*NH) { X = Kp; rowid -= BATCH*SEQ*NH; }
    const int h  = rowid & 15;
    const int bs = rowid >> 4;
    const int s  = bs & (SEQ-1);
    __hip_bfloat16* base = X + (size_t)bs*D_MODEL + h*HD;
    const float v0 = __bfloat162float(base[lane]);
    const float v1 = __bfloat162float(base[lane+64]);
    const float* tc = tab + (size_t)s*256;
    const float c0 = tc[lane],    sn0 = tc[128+lane];
    const float c1 = tc[64+lane], sn1 = tc[192+lane];
    const float a0 = __shfl(v0, (2*lane+1) & 63);
    const float a1 = __shfl(v1, (2*lane+1) & 63);
    const float pA = (lane >= 32) ? a1 : a0;
    const float b0 = __shfl(v0, (2*lane) & 63);
    const float b1 = __shfl(v1, (2*lane) & 63);
    const float pB = (lane >= 32) ? b1 : b0;
    base[lane]    = __float2bfloat16(v0*c0 - pA*sn0);
    base[lane+64] = __float2bfloat16(v1*c1 + pB*sn1);
}

// V [B*S][D_MODEL] -> Vt [B*H][HD][SEQ]
__global__ __launch_bounds__(256) void transpose_v(
    const unsigned short* __restrict__ V,
    unsigned short* __restrict__ Vt)
{
    __shared__ unsigned short t[64][66];
    const int bid = blockIdx.x;
    const int st = bid & 31;
    const int dt = (bid >> 5) & 1;
    const int bh = bid >> 6;
    const int b  = bh >> 4, h = bh & 15;
    const int tid = threadIdx.x;
    const int r = tid >> 5;
    const int c = tid & 31;
    #pragma unroll
    for (int i = 0; i < 8; i++) {
        const int row = i*8 + r;
        const unsigned int v = *(const unsigned int*)(
            V + (size_t)(b*SEQ + st*64 + row)*D_MODEL + h*HD + dt*64 + c*2);
        t[row][c*2]   = (unsigned short)(v & 0xffffu);
        t[row][c*2+1] = (unsigned short)(v >> 16);
    }
    __syncthreads();
    #pragma unroll
    for (int i = 0; i < 8; i++) {
        const int drow = i*8 + r;
        const unsigned int pk = (unsigned int)t[c*2][drow] | ((unsigned int)t[c*2+1][drow] << 16);
        *(unsigned int*)(Vt + ((size_t)bh*HD + dt*64 + drow)*SEQ + st*64 + c*2) = pk;
    }
}

// ---------------------------------------------------------------------------
// Flash attention v5: 512-thread blocks = 2 KV-groups x 4 waves (in-block
// split-KV). Group g covers kv [g*1024, g*1024+1024), chunk 32, dbuf LDS
// per group (32 KB). 16 waves/CU target. Merge halves via LDS at the end.
// ---------------------------------------------------------------------------
__global__ __launch_bounds__(512, 4) void flash_attn(
    const __hip_bfloat16* __restrict__ Qg,
    const __hip_bfloat16* __restrict__ Kg,
    const __hip_bfloat16* __restrict__ Vtg,
    __hip_bfloat16* __restrict__ ctx)
{
    __shared__ char lds_raw[65536];
    __hip_bfloat16* KsB = (__hip_bfloat16*)lds_raw;            // [g][buf][32*128]
    __hip_bfloat16* VsB = (__hip_bfloat16*)(lds_raw + 32768);  // [g][buf][128*32]

    const int tid  = threadIdx.x;
    const int w    = tid >> 6;       // 0..7
    const int g    = w >> 2;         // kv-half
    const int wg   = w & 3;          // wave-in-group
    const int lane = tid & 63;
    const int l31  = lane & 31;
    const int hi   = lane >> 5;
    const bool hib = (hi != 0);

    const int bid0 = blockIdx.x;                   // 512 blocks
    const int bid  = (bid0 & 7)*64 + (bid0 >> 3);  // XCD-aware swizzle (bijective)
    const int bh   = bid >> 4;                     // 0..31
    const int qt   = bid & 15;
    const int bi   = bh >> 4, h = bh & 15;
    const int q0   = qt*128 + wg*32;

    const float SC2 = 0.12751745f;   // log2(e)/sqrt(128)

    bf16x8 aq[8];
    {
        const __hip_bfloat16* qp =
            Qg + (size_t)(bi*SEQ + q0 + l31)*D_MODEL + h*HD + hi*8;
        #pragma unroll
        for (int ds = 0; ds < 8; ds++) aq[ds] = *(const bf16x8*)(qp + ds*16);
    }

    const __hip_bfloat16* kbase = Kg  + (size_t)(bi*SEQ + g*1024)*D_MODEL + h*HD;
    const __hip_bfloat16* vbase = Vtg + (size_t)bh*HD*SEQ + g*1024;
    __hip_bfloat16* KsG = KsB + g*8192;
    __hip_bfloat16* VsG = VsB + g*8192;

    // K rows: 256B, 16 slots, swz ^(row&15). V rows: 64B in 128B super-rows,
    // 4 slots, swz ^((row>>1)&3) -> 8 consecutive lanes cover all 8 slots.
#define STAGE(NB, KV) do {                                                            \
        _Pragma("unroll")                                                             \
        for (int i_ = 0; i_ < 2; i_++) {                                              \
            const int kr_ = wg*8 + i_*4 + (lane>>4);                                  \
            lds16(kbase + (size_t)((KV) + kr_)*D_MODEL + (((lane&15) ^ (kr_&15))*8),  \
                  KsG + (NB)*4096 + (wg*8 + i_*4)*128);                               \
        }                                                                             \
        _Pragma("unroll")                                                             \
        for (int i_ = 0; i_ < 2; i_++) {                                              \
            const int vr_ = wg*32 + i_*16 + (lane>>2);                                \
            lds16(vbase + (size_t)vr_*SEQ + (KV) + (((lane&3) ^ ((lane>>3)&3))*8),    \
                  VsG + (NB)*4096 + (wg*32 + i_*16)*32);                              \
        }                                                                             \
    } while (0)

    f32x16 o0 = {}, o1 = {}, o2 = {}, o3 = {};
    float ms = -1e30f, l_run = 0.0f;

    STAGE(0, 0);

    for (int t = 0; t < 32; t++) {
        const int cb = t & 1;
        __syncthreads();                          // stage(t) visible (vmcnt drained)
        if (t < 31) STAGE(cb^1, (t+1)*32);

        const __hip_bfloat16* Kc = KsG + cb*4096;
        const __hip_bfloat16* Vc = VsG + cb*4096;

        // ---- QK^T (swapped): S^T = mfma(A=K rows, B=Q rows) ----
        f32x16 p = {};
        __builtin_amdgcn_s_setprio(1);
        #pragma unroll
        for (int ds = 0; ds < 8; ds++) {
            const int sl = ((ds*2 + hi) ^ (l31 & 15)) * 8;
            const bf16x8 kf = *(const bf16x8*)&Kc[l31*128 + sl];
            p = __builtin_amdgcn_mfma_f32_32x32x16_bf16(kf, aq[ds], p, 0, 0, 0);
        }
        __builtin_amdgcn_s_setprio(0);

        // ---- online softmax in exp2 domain ----
        float pm = p[0];
        #pragma unroll
        for (int r = 1; r < 16; r++) pm = fmaxf(pm, p[r]);
        pm = fmaxf(pm, __shfl_xor(pm, 32));
        const float pms = pm * SC2;

        if (!__all(pms <= ms + 11.541560f)) {     // defer-max, THR=8 nats
            const float msn = fmaxf(ms, pms);
            const float al = __builtin_amdgcn_exp2f(ms - msn);
            l_run *= al;
            ms = msn;
            float alr[16];
            #pragma unroll
            for (int r = 0; r < 16; r++)
                alr[r] = __shfl(al, (r&3) + 8*(r>>2) + (hib ? 4 : 0));
            #pragma unroll
            for (int r = 0; r < 16; r++) {
                o0[r] *= alr[r]; o1[r] *= alr[r]; o2[r] *= alr[r]; o3[r] *= alr[r];
            }
        }

        #pragma unroll
        for (int r = 0; r < 16; r++)
            p[r] = __builtin_amdgcn_exp2f(__builtin_fmaf(p[r], SC2, -ms));
        float rs = 0.0f;
        #pragma unroll
        for (int r = 0; r < 16; r++) rs += p[r];
        rs += __shfl_xor(rs, 32);
        l_run += rs;

        // ---- PV: O += P·V ----
        __builtin_amdgcn_s_setprio(1);
#define PV_STEP(KS) do {                                                              \
            const unsigned int A0_ = pk2(p[8*(KS)+0], p[8*(KS)+1]);                   \
            const unsigned int A1_ = pk2(p[8*(KS)+2], p[8*(KS)+3]);                   \
            const unsigned int B0_ = pk2(p[8*(KS)+4], p[8*(KS)+5]);                   \
            const unsigned int B1_ = pk2(p[8*(KS)+6], p[8*(KS)+7]);                   \
            const unsigned int s0_ = hib ? A0_ : B0_;                                 \
            const unsigned int s1_ = hib ? A1_ : B1_;                                 \
            const unsigned int r0_ = (unsigned int)__shfl_xor((int)s0_, 32);          \
            const unsigned int r1_ = (unsigned int)__shfl_xor((int)s1_, 32);          \
            u32x4 au_;                                                                \
            au_.x = hib ? r0_ : A0_;  au_.y = hib ? r1_ : A1_;                        \
            au_.z = hib ? B0_ : r0_;  au_.w = hib ? B1_ : r1_;                        \
            const bf16x8 pa_ = *(const bf16x8*)&au_;                                  \
            const int ko_ = (((KS)*2 + hi) ^ ((l31>>1) & 3)) * 8;                     \
            o0 = __builtin_amdgcn_mfma_f32_32x32x16_bf16(pa_,                         \
                     *(const bf16x8*)&Vc[(  0 + l31)*32 + ko_], o0, 0, 0, 0);         \
            o1 = __builtin_amdgcn_mfma_f32_32x32x16_bf16(pa_,                         \
                     *(const bf16x8*)&Vc[( 32 + l31)*32 + ko_], o1, 0, 0, 0);         \
            o2 = __builtin_amdgcn_mfma_f32_32x32x16_bf16(pa_,                         \
                     *(const bf16x8*)&Vc[( 64 + l31)*32 + ko_], o2, 0, 0, 0);         \
            o3 = __builtin_amdgcn_mfma_f32_32x32x16_bf16(pa_,                         \
                     *(const bf16x8*)&Vc[( 96 + l31)*32 + ko_], o3, 0, 0, 0);         \
        } while (0)
        PV_STEP(0); PV_STEP(1);
#undef PV_STEP
        __builtin_amdgcn_s_setprio(0);
    }
#undef STAGE

    // ---- merge the two KV-halves (pairs: w <-> w+4), two phases over LDS ----
    float* scratch = (float*)lds_raw;             // 64 KB scratch, stage bufs dead
    const int slot = w & 1;
    #pragma unroll 1
    for (int ph = 0; ph < 2; ph++) {
        __syncthreads();
        if ((w >> 1) == ph + 2) {                 // upper waves 4,5 then 6,7
            float* dst = scratch + slot*4224 + lane*66;
            #pragma unroll
            for (int r = 0; r < 16; r++) {
                dst[r]    = o0[r];
                dst[16+r] = o1[r];
                dst[32+r] = o2[r];
                dst[48+r] = o3[r];
            }
            dst[64] = ms; dst[65] = l_run;
        }
        __syncthreads();
        if (w < 4 && (w >> 1) == ph) {            // lower waves 0,1 then 2,3
            const float* src = scratch + slot*4224 + lane*66;
            const float m1 = src[64], l1 = src[65];
            const float mstar = fmaxf(ms, m1);
            const float f0 = __builtin_amdgcn_exp2f(ms - mstar);
            const float f1 = __builtin_amdgcn_exp2f(m1 - mstar);
            const float inv = 1.0f / (l_run*f0 + l1*f1);
            const float f0i = f0*inv, f1i = f1*inv;
            #pragma unroll
            for (int r = 0; r < 16; r++) {
                const int rp = (r&3) + 8*(r>>2) + (hib ? 4 : 0);
                const float f0r = __shfl(f0i, rp);
                const float f1r = __shfl(f1i, rp);
                __hip_bfloat16* cp = ctx + (size_t)(bi*SEQ + q0 + rp)*D_MODEL + h*HD + l31;
                cp[0]  = __float2bfloat16(o0[r]*f0r + src[ 0+r]*f1r);
                cp[32] = __float2bfloat16(o1[r]*f0r + src[16+r]*f1r);
                cp[64] = __float2bfloat16(o2[r]*f0r + src[32+r]*f1r);
                cp[96] = __float2bfloat16(o3[r]*f0r + src[48+r]*f1r);
            }
        }
    }
}

extern "C" void kernel_launch(void* const* d_in, const int* in_sizes, int n_in,
                              void* d_out, int out_size, void* d_ws, size_t ws_size,
                              hipStream_t stream)
{
    const float* query = (const float*)d_in[0];
    const float* key   = (const float*)d_in[1];
    const float* value = (const float*)d_in[2];
    const float* Wq    = (const float*)d_in[3];
    const float* bq    = (const float*)d_in[4];
    const float* Wk    = (const float*)d_in[5];
    const float* bk    = (const float*)d_in[6];
    const float* Wv    = (const float*)d_in[7];
    const float* bv    = (const float*)d_in[8];
    const float* Wo    = (const float*)d_in[9];
    const float* bo    = (const float*)d_in[10];
    float* out = (float*)d_out;

    char* ws = (char*)d_ws;
    const size_t MB = 1024*1024;
    __hip_bfloat16* qb  = (__hip_bfloat16*)(ws);
    __hip_bfloat16* kbuf= (__hip_bfloat16*)(ws + 16*MB);
    __hip_bfloat16* vbuf= (__hip_bfloat16*)(ws + 32*MB);
    __hip_bfloat16* Qp  = (__hip_bfloat16*)(ws + 48*MB);
    __hip_bfloat16* Kp  = (__hip_bfloat16*)(ws + 64*MB);
    __hip_bfloat16* Vp  = (__hip_bfloat16*)(ws + 80*MB);
    __hip_bfloat16* Vt  = (__hip_bfloat16*)(ws + 96*MB);
    __hip_bfloat16* ctx = (__hip_bfloat16*)(ws + 112*MB);
    __hip_bfloat16* Wqb = (__hip_bfloat16*)(ws + 128*MB);
    __hip_bfloat16* Wkb = (__hip_bfloat16*)(ws + 136*MB);
    __hip_bfloat16* Wvb = (__hip_bfloat16*)(ws + 144*MB);
    __hip_bfloat16* Wob = (__hip_bfloat16*)(ws + 152*MB);
    float*          tab = (float*)         (ws + 160*MB);

    cvt_all<<<40960, 256, 0, stream>>>(query, key, value, Wq, Wk, Wv, Wo,
        (unsigned short*)qb, (unsigned short*)kbuf, (unsigned short*)vbuf,
        (unsigned short*)Wqb, (unsigned short*)Wkb, (unsigned short*)Wvb,
        (unsigned short*)Wob);

    rope_table<<<SEQ*HD/256, 256, 0, stream>>>(tab);

    const int gemm_grid = (MROWS/128)*(D_MODEL/128);
    gemm_bt_bias<__hip_bfloat16><<<gemm_grid, 256, 0, stream>>>(qb,   Wqb, bq, Qp, MROWS, D_MODEL, D_MODEL);
    gemm_bt_bias<__hip_bfloat16><<<gemm_grid, 256, 0, stream>>>(kbuf, Wkb, bk, Kp, MROWS, D_MODEL, D_MODEL);
    gemm_bt_bias<__hip_bfloat16><<<gemm_grid, 256, 0, stream>>>(vbuf, Wvb, bv, Vp, MROWS, D_MODEL, D_MODEL);

    rope_apply_qk<<<2*BATCH*SEQ*NH/4, 256, 0, stream>>>(Qp, Kp, tab);
    transpose_v<<<BATCH*NH*2*(SEQ/64), 256, 0, stream>>>((const unsigned short*)Vp, (unsigned short*)Vt);

    flash_attn<<<BATCH*NH*(SEQ/128), 512, 0, stream>>>(Qp, Kp, Vt, ctx);

    gemm_bt_bias<float><<<gemm_grid, 256, 0, stream>>>(ctx, Wob, bo, out, MROWS, D_MODEL, D_MODEL);
}

// Round 6
// 366.465 us; speedup vs baseline: 1.2235x; 1.0858x over previous
//
#include <hip/hip_runtime.h>
#include <hip/hip_bf16.h>

#define D_MODEL 2048
#define SEQ     2048
#define BATCH   2
#define NH      16
#define HD      128
#define MROWS   (BATCH*SEQ)   // 4096

typedef __attribute__((ext_vector_type(8)))  short bf16x8;
typedef __attribute__((ext_vector_type(4)))  float f32x4;
typedef __attribute__((ext_vector_type(16))) float f32x16;
typedef __attribute__((ext_vector_type(4)))  unsigned int u32x4;

// async global->LDS, 16B per lane. LDS dest is wave-uniform base + lane*16 (implicit).
static __device__ __forceinline__ void lds16(const void* g, void* l) {
    __builtin_amdgcn_global_load_lds(
        (const __attribute__((address_space(1))) void*)g,
        (__attribute__((address_space(3))) void*)l,
        16, 0, 0);
}

static __device__ __forceinline__ unsigned int pk2(float a, float b) {
    const unsigned int lo = __bfloat16_as_ushort(__float2bfloat16(a));
    const unsigned int hh = __bfloat16_as_ushort(__float2bfloat16(b));
    return lo | (hh << 16);
}

// ---------------- all f32->bf16 conversions in one launch ----------------
__global__ __launch_bounds__(256) void cvt_all(
    const float* __restrict__ q,  const float* __restrict__ k,  const float* __restrict__ v,
    const float* __restrict__ wq, const float* __restrict__ wk, const float* __restrict__ wv,
    const float* __restrict__ wo,
    unsigned short* __restrict__ qb, unsigned short* __restrict__ kb, unsigned short* __restrict__ vb,
    unsigned short* __restrict__ wqb, unsigned short* __restrict__ wkb,
    unsigned short* __restrict__ wvb, unsigned short* __restrict__ wob)
{
    const int b = blockIdx.x;
    const float* src; unsigned short* dst; int idx;
    if (b < 24576) {
        const int s = b >> 13;
        idx = (b & 8191)*256 + threadIdx.x;
        src = (s==0) ? q : (s==1) ? k : v;
        dst = (s==0) ? qb : (s==1) ? kb : vb;
    } else {
        const int bb = b - 24576;
        const int s = bb >> 12;
        idx = (bb & 4095)*256 + threadIdx.x;
        src = (s==0) ? wq : (s==1) ? wk : (s==2) ? wv : wo;
        dst = (s==0) ? wqb : (s==1) ? wkb : (s==2) ? wvb : wob;
    }
    const float4 a = ((const float4*)src)[idx];
    ushort4 o;
    o.x = __bfloat16_as_ushort(__float2bfloat16(a.x));
    o.y = __bfloat16_as_ushort(__float2bfloat16(a.y));
    o.z = __bfloat16_as_ushort(__float2bfloat16(a.z));
    o.w = __bfloat16_as_ushort(__float2bfloat16(a.w));
    ((ushort4*)dst)[idx] = o;
}

// ---------------- GEMM: C = A·W^T + bias, 128x128 tile, BK=32 ----------------
// 4-deep LDS pipeline (stage t+2 while computing t), counted vmcnt(4), raw barriers.
template <typename OutT>
__global__ __launch_bounds__(256, 2) void gemm_bt_bias(
    const __hip_bfloat16* __restrict__ A,
    const __hip_bfloat16* __restrict__ W,
    const float* __restrict__ bias,
    OutT* __restrict__ C,
    const int M, const int N, const int K)
{
    __shared__ __hip_bfloat16 As[4][128*32];
    __shared__ __hip_bfloat16 Bs[4][128*32];
    const int nb   = N >> 7;
    const int bm   = blockIdx.x / nb;
    const int bn   = blockIdx.x % nb;
    const int tid  = threadIdx.x;
    const int lane = tid & 63;
    const int w    = tid >> 6;
    const int wr   = (w >> 1) * 64;
    const int wc   = (w & 1) * 64;
    const int l15  = lane & 15, l4 = lane >> 4;

    const int srow = w*32 + (lane>>2);
    const __hip_bfloat16* ga = A + (size_t)(bm*128 + srow)*K + (lane&3)*8;
    const __hip_bfloat16* gb = W + (size_t)(bn*128 + srow)*K + (lane&3)*8;

#define GSTAGE(Q_, KT_) do {                                          \
        lds16(ga + (KT_),                &As[Q_][(w*32)*32]);         \
        lds16(ga + (KT_) + (size_t)16*K, &As[Q_][(w*32+16)*32]);      \
        lds16(gb + (KT_),                &Bs[Q_][(w*32)*32]);         \
        lds16(gb + (KT_) + (size_t)16*K, &Bs[Q_][(w*32+16)*32]);      \
    } while (0)

    f32x4 acc[4][4] = {};
    const int NT = K >> 5;

    GSTAGE(0, 0);
    GSTAGE(1, 32);
    asm volatile("s_waitcnt vmcnt(4)" ::: "memory");
    __builtin_amdgcn_s_barrier();

    for (int t = 0; t < NT; ++t) {
        const int q = t & 3;
        if (t + 2 < NT) GSTAGE((t+2)&3, (t+2)*32);
        bf16x8 af[4], bfr[4];
        #pragma unroll
        for (int i = 0; i < 4; i++) {
            af[i]  = *(const bf16x8*)&As[q][(wr + i*16 + l15)*32 + l4*8];
            bfr[i] = *(const bf16x8*)&Bs[q][(wc + i*16 + l15)*32 + l4*8];
        }
        __builtin_amdgcn_s_setprio(1);
        #pragma unroll
        for (int i = 0; i < 4; i++)
            #pragma unroll
            for (int j = 0; j < 4; j++)
                acc[i][j] = __builtin_amdgcn_mfma_f32_16x16x32_bf16(af[i], bfr[j], acc[i][j], 0, 0, 0);
        __builtin_amdgcn_s_setprio(0);
        if (t + 2 < NT) {
            asm volatile("s_waitcnt vmcnt(4)" ::: "memory");
            __builtin_amdgcn_s_barrier();
        } else if (t + 1 < NT) {
            asm volatile("s_waitcnt vmcnt(0)" ::: "memory");
            __builtin_amdgcn_s_barrier();
        }
    }
#undef GSTAGE

    float bv[4];
    #pragma unroll
    for (int j = 0; j < 4; j++)
        bv[j] = bias[bn*128 + wc + j*16 + l15];
    #pragma unroll
    for (int i = 0; i < 4; i++) {
        #pragma unroll
        for (int j = 0; j < 4; j++) {
            const int col = bn*128 + wc + j*16 + l15;
            #pragma unroll
            for (int r = 0; r < 4; r++) {
                const int row = bm*128 + wr + i*16 + l4*4 + r;
                const float v = acc[i][j][r] + bv[j];
                if constexpr (sizeof(OutT) == 2)
                    C[(size_t)row*N + col] = OutT(__float2bfloat16(v));
                else
                    C[(size_t)row*N + col] = OutT(v);
            }
        }
    }
}

// sincos table
__global__ __launch_bounds__(256) void rope_table(float* __restrict__ tab)
{
    const int i = blockIdx.x*256 + threadIdx.x;
    const int s = i >> 7, d = i & 127;
    const float invf = expf(-(float)d * (9.210340371976184f / 1024.0f));
    const float f = (float)s * invf;
    tab[(size_t)s*256 + d]       = cosf(f);
    tab[(size_t)s*256 + 128 + d] = sinf(f);
}

// interleaved-rotate_half RoPE, in place, Q then K in one launch.
__global__ __launch_bounds__(256) void rope_apply_qk(
    __hip_bfloat16* __restrict__ Qp, __hip_bfloat16* __restrict__ Kp,
    const float* __restrict__ tab)
{
    const int tid  = threadIdx.x;
    const int w    = tid >> 6, lane = tid & 63;
    int rowid = blockIdx.x*4 + w;
    __hip_bfloat16* X = Qp;
    if (rowid >= BATCH*SEQ*NH) { X = Kp; rowid -= BATCH*SEQ*NH; }
    const int h  = rowid & 15;
    const int bs = rowid >> 4;
    const int s  = bs & (SEQ-1);
    __hip_bfloat16* base = X + (size_t)bs*D_MODEL + h*HD;
    const float v0 = __bfloat162float(base[lane]);
    const float v1 = __bfloat162float(base[lane+64]);
    const float* tc = tab + (size_t)s*256;
    const float c0 = tc[lane],    sn0 = tc[128+lane];
    const float c1 = tc[64+lane], sn1 = tc[192+lane];
    const float a0 = __shfl(v0, (2*lane+1) & 63);
    const float a1 = __shfl(v1, (2*lane+1) & 63);
    const float pA = (lane >= 32) ? a1 : a0;
    const float b0 = __shfl(v0, (2*lane) & 63);
    const float b1 = __shfl(v1, (2*lane) & 63);
    const float pB = (lane >= 32) ? b1 : b0;
    base[lane]    = __float2bfloat16(v0*c0 - pA*sn0);
    base[lane+64] = __float2bfloat16(v1*c1 + pB*sn1);
}

// V [B*S][D_MODEL] -> Vt [B*H][HD][SEQ]
__global__ __launch_bounds__(256) void transpose_v(
    const unsigned short* __restrict__ V,
    unsigned short* __restrict__ Vt)
{
    __shared__ unsigned short t[64][66];
    const int bid = blockIdx.x;
    const int st = bid & 31;
    const int dt = (bid >> 5) & 1;
    const int bh = bid >> 6;
    const int b  = bh >> 4, h = bh & 15;
    const int tid = threadIdx.x;
    const int r = tid >> 5;
    const int c = tid & 31;
    #pragma unroll
    for (int i = 0; i < 8; i++) {
        const int row = i*8 + r;
        const unsigned int v = *(const unsigned int*)(
            V + (size_t)(b*SEQ + st*64 + row)*D_MODEL + h*HD + dt*64 + c*2);
        t[row][c*2]   = (unsigned short)(v & 0xffffu);
        t[row][c*2+1] = (unsigned short)(v >> 16);
    }
    __syncthreads();
    #pragma unroll
    for (int i = 0; i < 8; i++) {
        const int drow = i*8 + r;
        const unsigned int pk = (unsigned int)t[c*2][drow] | ((unsigned int)t[c*2+1][drow] << 16);
        *(unsigned int*)(Vt + ((size_t)bh*HD + dt*64 + drow)*SEQ + st*64 + c*2) = pk;
    }
}

// ---------------------------------------------------------------------------
// Flash attention v6 = v5 with the VGPR cap removed (no min-blocks arg).
// 512-thread blocks = 2 KV-groups x 4 waves (in-block split-KV).
// ---------------------------------------------------------------------------
__global__ __launch_bounds__(512) void flash_attn(
    const __hip_bfloat16* __restrict__ Qg,
    const __hip_bfloat16* __restrict__ Kg,
    const __hip_bfloat16* __restrict__ Vtg,
    __hip_bfloat16* __restrict__ ctx)
{
    __shared__ char lds_raw[65536];
    __hip_bfloat16* KsB = (__hip_bfloat16*)lds_raw;            // [g][buf][32*128]
    __hip_bfloat16* VsB = (__hip_bfloat16*)(lds_raw + 32768);  // [g][buf][128*32]

    const int tid  = threadIdx.x;
    const int w    = tid >> 6;       // 0..7
    const int g    = w >> 2;         // kv-half
    const int wg   = w & 3;          // wave-in-group
    const int lane = tid & 63;
    const int l31  = lane & 31;
    const int hi   = lane >> 5;
    const bool hib = (hi != 0);

    const int bid0 = blockIdx.x;                   // 512 blocks
    const int bid  = (bid0 & 7)*64 + (bid0 >> 3);  // XCD-aware swizzle (bijective)
    const int bh   = bid >> 4;                     // 0..31
    const int qt   = bid & 15;
    const int bi   = bh >> 4, h = bh & 15;
    const int q0   = qt*128 + wg*32;

    const float SC2 = 0.12751745f;   // log2(e)/sqrt(128)

    bf16x8 aq[8];
    {
        const __hip_bfloat16* qp =
            Qg + (size_t)(bi*SEQ + q0 + l31)*D_MODEL + h*HD + hi*8;
        #pragma unroll
        for (int ds = 0; ds < 8; ds++) aq[ds] = *(const bf16x8*)(qp + ds*16);
    }

    const __hip_bfloat16* kbase = Kg  + (size_t)(bi*SEQ + g*1024)*D_MODEL + h*HD;
    const __hip_bfloat16* vbase = Vtg + (size_t)bh*HD*SEQ + g*1024;
    __hip_bfloat16* KsG = KsB + g*8192;
    __hip_bfloat16* VsG = VsB + g*8192;

    // K rows: 256B, 16 slots, swz ^(row&15). V rows: 64B in 128B super-rows,
    // 4 slots, swz ^((row>>1)&3) -> 8 consecutive lanes cover all 8 slots.
#define STAGE(NB, KV) do {                                                            \
        _Pragma("unroll")                                                             \
        for (int i_ = 0; i_ < 2; i_++) {                                              \
            const int kr_ = wg*8 + i_*4 + (lane>>4);                                  \
            lds16(kbase + (size_t)((KV) + kr_)*D_MODEL + (((lane&15) ^ (kr_&15))*8),  \
                  KsG + (NB)*4096 + (wg*8 + i_*4)*128);                               \
        }                                                                             \
        _Pragma("unroll")                                                             \
        for (int i_ = 0; i_ < 2; i_++) {                                              \
            const int vr_ = wg*32 + i_*16 + (lane>>2);                                \
            lds16(vbase + (size_t)vr_*SEQ + (KV) + (((lane&3) ^ ((lane>>3)&3))*8),    \
                  VsG + (NB)*4096 + (wg*32 + i_*16)*32);                              \
        }                                                                             \
    } while (0)

    f32x16 o0 = {}, o1 = {}, o2 = {}, o3 = {};
    float ms = -1e30f, l_run = 0.0f;

    STAGE(0, 0);

    for (int t = 0; t < 32; t++) {
        const int cb = t & 1;
        __syncthreads();                          // stage(t) visible (vmcnt drained)
        if (t < 31) STAGE(cb^1, (t+1)*32);

        const __hip_bfloat16* Kc = KsG + cb*4096;
        const __hip_bfloat16* Vc = VsG + cb*4096;

        // ---- QK^T (swapped): S^T = mfma(A=K rows, B=Q rows) ----
        f32x16 p = {};
        __builtin_amdgcn_s_setprio(1);
        #pragma unroll
        for (int ds = 0; ds < 8; ds++) {
            const int sl = ((ds*2 + hi) ^ (l31 & 15)) * 8;
            const bf16x8 kf = *(const bf16x8*)&Kc[l31*128 + sl];
            p = __builtin_amdgcn_mfma_f32_32x32x16_bf16(kf, aq[ds], p, 0, 0, 0);
        }
        __builtin_amdgcn_s_setprio(0);

        // ---- online softmax in exp2 domain ----
        float pm = p[0];
        #pragma unroll
        for (int r = 1; r < 16; r++) pm = fmaxf(pm, p[r]);
        pm = fmaxf(pm, __shfl_xor(pm, 32));
        const float pms = pm * SC2;

        if (!__all(pms <= ms + 11.541560f)) {     // defer-max, THR=8 nats
            const float msn = fmaxf(ms, pms);
            const float al = __builtin_amdgcn_exp2f(ms - msn);
            l_run *= al;
            ms = msn;
            float alr[16];
            #pragma unroll
            for (int r = 0; r < 16; r++)
                alr[r] = __shfl(al, (r&3) + 8*(r>>2) + (hib ? 4 : 0));
            #pragma unroll
            for (int r = 0; r < 16; r++) {
                o0[r] *= alr[r]; o1[r] *= alr[r]; o2[r] *= alr[r]; o3[r] *= alr[r];
            }
        }

        #pragma unroll
        for (int r = 0; r < 16; r++)
            p[r] = __builtin_amdgcn_exp2f(__builtin_fmaf(p[r], SC2, -ms));
        float rs = 0.0f;
        #pragma unroll
        for (int r = 0; r < 16; r++) rs += p[r];
        rs += __shfl_xor(rs, 32);
        l_run += rs;

        // ---- PV: O += P·V ----
        __builtin_amdgcn_s_setprio(1);
#define PV_STEP(KS) do {                                                              \
            const unsigned int A0_ = pk2(p[8*(KS)+0], p[8*(KS)+1]);                   \
            const unsigned int A1_ = pk2(p[8*(KS)+2], p[8*(KS)+3]);                   \
            const unsigned int B0_ = pk2(p[8*(KS)+4], p[8*(KS)+5]);                   \
            const unsigned int B1_ = pk2(p[8*(KS)+6], p[8*(KS)+7]);                   \
            const unsigned int s0_ = hib ? A0_ : B0_;                                 \
            const unsigned int s1_ = hib ? A1_ : B1_;                                 \
            const unsigned int r0_ = (unsigned int)__shfl_xor((int)s0_, 32);          \
            const unsigned int r1_ = (unsigned int)__shfl_xor((int)s1_, 32);          \
            u32x4 au_;                                                                \
            au_.x = hib ? r0_ : A0_;  au_.y = hib ? r1_ : A1_;                        \
            au_.z = hib ? B0_ : r0_;  au_.w = hib ? B1_ : r1_;                        \
            const bf16x8 pa_ = *(const bf16x8*)&au_;                                  \
            const int ko_ = (((KS)*2 + hi) ^ ((l31>>1) & 3)) * 8;                     \
            o0 = __builtin_amdgcn_mfma_f32_32x32x16_bf16(pa_,                         \
                     *(const bf16x8*)&Vc[(  0 + l31)*32 + ko_], o0, 0, 0, 0);         \
            o1 = __builtin_amdgcn_mfma_f32_32x32x16_bf16(pa_,                         \
                     *(const bf16x8*)&Vc[( 32 + l31)*32 + ko_], o1, 0, 0, 0);         \
            o2 = __builtin_amdgcn_mfma_f32_32x32x16_bf16(pa_,                         \
                     *(const bf16x8*)&Vc[( 64 + l31)*32 + ko_], o2, 0, 0, 0);         \
            o3 = __builtin_amdgcn_mfma_f32_32x32x16_bf16(pa_,                         \
                     *(const bf16x8*)&Vc[( 96 + l31)*32 + ko_], o3, 0, 0, 0);         \
        } while (0)
        PV_STEP(0); PV_STEP(1);
#undef PV_STEP
        __builtin_amdgcn_s_setprio(0);
    }
#undef STAGE

    // ---- merge the two KV-halves (pairs: w <-> w+4), two phases over LDS ----
    float* scratch = (float*)lds_raw;             // 64 KB scratch, stage bufs dead
    const int slot = w & 1;
    #pragma unroll 1
    for (int ph = 0; ph < 2; ph++) {
        __syncthreads();
        if ((w >> 1) == ph + 2) {                 // upper waves 4,5 then 6,7
            float* dst = scratch + slot*4224 + lane*66;
            #pragma unroll
            for (int r = 0; r < 16; r++) {
                dst[r]    = o0[r];
                dst[16+r] = o1[r];
                dst[32+r] = o2[r];
                dst[48+r] = o3[r];
            }
            dst[64] = ms; dst[65] = l_run;
        }
        __syncthreads();
        if (w < 4 && (w >> 1) == ph) {            // lower waves 0,1 then 2,3
            const float* src = scratch + slot*4224 + lane*66;
            const float m1 = src[64], l1 = src[65];
            const float mstar = fmaxf(ms, m1);
            const float f0 = __builtin_amdgcn_exp2f(ms - mstar);
            const float f1 = __builtin_amdgcn_exp2f(m1 - mstar);
            const float inv = 1.0f / (l_run*f0 + l1*f1);
            const float f0i = f0*inv, f1i = f1*inv;
            #pragma unroll
            for (int r = 0; r < 16; r++) {
                const int rp = (r&3) + 8*(r>>2) + (hib ? 4 : 0);
                const float f0r = __shfl(f0i, rp);
                const float f1r = __shfl(f1i, rp);
                __hip_bfloat16* cp = ctx + (size_t)(bi*SEQ + q0 + rp)*D_MODEL + h*HD + l31;
                cp[0]  = __float2bfloat16(o0[r]*f0r + src[ 0+r]*f1r);
                cp[32] = __float2bfloat16(o1[r]*f0r + src[16+r]*f1r);
                cp[64] = __float2bfloat16(o2[r]*f0r + src[32+r]*f1r);
                cp[96] = __float2bfloat16(o3[r]*f0r + src[48+r]*f1r);
            }
        }
    }
}

extern "C" void kernel_launch(void* const* d_in, const int* in_sizes, int n_in,
                              void* d_out, int out_size, void* d_ws, size_t ws_size,
                              hipStream_t stream)
{
    const float* query = (const float*)d_in[0];
    const float* key   = (const float*)d_in[1];
    const float* value = (const float*)d_in[2];
    const float* Wq    = (const float*)d_in[3];
    const float* bq    = (const float*)d_in[4];
    const float* Wk    = (const float*)d_in[5];
    const float* bk    = (const float*)d_in[6];
    const float* Wv    = (const float*)d_in[7];
    const float* bv    = (const float*)d_in[8];
    const float* Wo    = (const float*)d_in[9];
    const float* bo    = (const float*)d_in[10];
    float* out = (float*)d_out;

    char* ws = (char*)d_ws;
    const size_t MB = 1024*1024;
    __hip_bfloat16* qb  = (__hip_bfloat16*)(ws);
    __hip_bfloat16* kbuf= (__hip_bfloat16*)(ws + 16*MB);
    __hip_bfloat16* vbuf= (__hip_bfloat16*)(ws + 32*MB);
    __hip_bfloat16* Qp  = (__hip_bfloat16*)(ws + 48*MB);
    __hip_bfloat16* Kp  = (__hip_bfloat16*)(ws + 64*MB);
    __hip_bfloat16* Vp  = (__hip_bfloat16*)(ws + 80*MB);
    __hip_bfloat16* Vt  = (__hip_bfloat16*)(ws + 96*MB);
    __hip_bfloat16* ctx = (__hip_bfloat16*)(ws + 112*MB);
    __hip_bfloat16* Wqb = (__hip_bfloat16*)(ws + 128*MB);
    __hip_bfloat16* Wkb = (__hip_bfloat16*)(ws + 136*MB);
    __hip_bfloat16* Wvb = (__hip_bfloat16*)(ws + 144*MB);
    __hip_bfloat16* Wob = (__hip_bfloat16*)(ws + 152*MB);
    float*          tab = (float*)         (ws + 160*MB);

    cvt_all<<<40960, 256, 0, stream>>>(query, key, value, Wq, Wk, Wv, Wo,
        (unsigned short*)qb, (unsigned short*)kbuf, (unsigned short*)vbuf,
        (unsigned short*)Wqb, (unsigned short*)Wkb, (unsigned short*)Wvb,
        (unsigned short*)Wob);

    rope_table<<<SEQ*HD/256, 256, 0, stream>>>(tab);

    const int gemm_grid = (MROWS/128)*(D_MODEL/128);
    gemm_bt_bias<__hip_bfloat16><<<gemm_grid, 256, 0, stream>>>(qb,   Wqb, bq, Qp, MROWS, D_MODEL, D_MODEL);
    gemm_bt_bias<__hip_bfloat16><<<gemm_grid, 256, 0, stream>>>(kbuf, Wkb, bk, Kp, MROWS, D_MODEL, D_MODEL);
    gemm_bt_bias<__hip_bfloat16><<<gemm_grid, 256, 0, stream>>>(vbuf, Wvb, bv, Vp, MROWS, D_MODEL, D_MODEL);

    rope_apply_qk<<<2*BATCH*SEQ*NH/4, 256, 0, stream>>>(Qp, Kp, tab);
    transpose_v<<<BATCH*NH*2*(SEQ/64), 256, 0, stream>>>((const unsigned short*)Vp, (unsigned short*)Vt);

    flash_attn<<<BATCH*NH*(SEQ/128), 512, 0, stream>>>(Qp, Kp, Vt, ctx);

    gemm_bt_bias<float><<<gemm_grid, 256, 0, stream>>>(ctx, Wob, bo, out, MROWS, D_MODEL, D_MODEL);
}

// Round 7
// 330.733 us; speedup vs baseline: 1.3557x; 1.1080x over previous
//
#include <hip/hip_runtime.h>
#include <hip/hip_bf16.h>

#define D_MODEL 2048
#define SEQ     2048
#define BATCH   2
#define NH      16
#define HD      128
#define MROWS   (BATCH*SEQ)   // 4096

typedef __attribute__((ext_vector_type(8)))  short bf16x8;
typedef __attribute__((ext_vector_type(4)))  float f32x4;
typedef __attribute__((ext_vector_type(16))) float f32x16;
typedef __attribute__((ext_vector_type(4)))  unsigned int u32x4;

// async global->LDS, 16B per lane. LDS dest is wave-uniform base + lane*16 (implicit).
static __device__ __forceinline__ void lds16(const void* g, void* l) {
    __builtin_amdgcn_global_load_lds(
        (const __attribute__((address_space(1))) void*)g,
        (__attribute__((address_space(3))) void*)l,
        16, 0, 0);
}

static __device__ __forceinline__ unsigned int pk2(float a, float b) {
    const unsigned int lo = __bfloat16_as_ushort(__float2bfloat16(a));
    const unsigned int hh = __bfloat16_as_ushort(__float2bfloat16(b));
    return lo | (hh << 16);
}
static __device__ __forceinline__ unsigned short bfu(float a) {
    return __bfloat16_as_ushort(__float2bfloat16(a));
}

// ---------------- all f32->bf16 conversions in one launch ----------------
__global__ __launch_bounds__(256) void cvt_all(
    const float* __restrict__ q,  const float* __restrict__ k,  const float* __restrict__ v,
    const float* __restrict__ wq, const float* __restrict__ wk, const float* __restrict__ wv,
    const float* __restrict__ wo,
    unsigned short* __restrict__ qb, unsigned short* __restrict__ kb, unsigned short* __restrict__ vb,
    unsigned short* __restrict__ wqb, unsigned short* __restrict__ wkb,
    unsigned short* __restrict__ wvb, unsigned short* __restrict__ wob)
{
    const int b = blockIdx.x;
    const float* src; unsigned short* dst; int idx;
    if (b < 24576) {
        const int s = b >> 13;
        idx = (b & 8191)*256 + threadIdx.x;
        src = (s==0) ? q : (s==1) ? k : v;
        dst = (s==0) ? qb : (s==1) ? kb : vb;
    } else {
        const int bb = b - 24576;
        const int s = bb >> 12;
        idx = (bb & 4095)*256 + threadIdx.x;
        src = (s==0) ? wq : (s==1) ? wk : (s==2) ? wv : wo;
        dst = (s==0) ? wqb : (s==1) ? wkb : (s==2) ? wvb : wob;
    }
    const float4 a = ((const float4*)src)[idx];
    ushort4 o;
    o.x = bfu(a.x); o.y = bfu(a.y); o.z = bfu(a.z); o.w = bfu(a.w);
    ((ushort4*)dst)[idx] = o;
}

// sincos table: tab[s*256 + d] = cos, tab[s*256+128+d] = sin
__global__ __launch_bounds__(256) void rope_table(float* __restrict__ tab)
{
    const int i = blockIdx.x*256 + threadIdx.x;
    const int s = i >> 7, d = i & 127;
    const float invf = expf(-(float)d * (9.210340371976184f / 1024.0f));
    const float f = (float)s * invf;
    tab[(size_t)s*256 + d]       = cosf(f);
    tab[(size_t)s*256 + 128 + d] = sinf(f);
}

// ---------------- fused QKV GEMM + bias + RoPE(Q,K) + transpose(V) ----------
// N = 3*2048; each 128-col tile = one (matrix, head). 4-deep pipeline, BK=32.
__global__ __launch_bounds__(256, 2) void gemm_qkv_fused(
    const __hip_bfloat16* __restrict__ Aq,
    const __hip_bfloat16* __restrict__ Ak,
    const __hip_bfloat16* __restrict__ Av,
    const __hip_bfloat16* __restrict__ Wq, const __hip_bfloat16* __restrict__ Wk,
    const __hip_bfloat16* __restrict__ Wv,
    const float* __restrict__ bq, const float* __restrict__ bk, const float* __restrict__ bv,
    const float* __restrict__ tab,
    __hip_bfloat16* __restrict__ Qp, __hip_bfloat16* __restrict__ Kp,
    __hip_bfloat16* __restrict__ Vt)
{
    __shared__ char smem[65536];
    __hip_bfloat16* As = (__hip_bfloat16*)smem;            // [4][128*32]
    __hip_bfloat16* Bs = (__hip_bfloat16*)(smem + 32768);  // [4][128*32]

    const int K    = D_MODEL;
    const int bm   = blockIdx.x / 48;
    const int bn   = blockIdx.x % 48;
    const int mat  = bn >> 4;        // 0=Q 1=K 2=V
    const int hd   = bn & 15;
    const __hip_bfloat16* A  = (mat==0) ? Aq : (mat==1) ? Ak : Av;
    const __hip_bfloat16* W  = (mat==0) ? Wq : (mat==1) ? Wk : Wv;
    const float*          bi = (mat==0) ? bq : (mat==1) ? bk : bv;

    const int tid  = threadIdx.x;
    const int lane = tid & 63;
    const int w    = tid >> 6;
    const int wr   = (w >> 1) * 64;
    const int wc   = (w & 1) * 64;
    const int l15  = lane & 15, l4 = lane >> 4;

    const int srow = w*32 + (lane>>2);
    const __hip_bfloat16* ga = A + (size_t)(bm*128 + srow)*K + (lane&3)*8;
    const __hip_bfloat16* gb = W + (size_t)(hd*128 + srow)*K + (lane&3)*8;

#define GSTAGE(Q_, KT_) do {                                               \
        lds16(ga + (KT_),                &As[(Q_)*4096 + (w*32)*32]);      \
        lds16(ga + (KT_) + (size_t)16*K, &As[(Q_)*4096 + (w*32+16)*32]);   \
        lds16(gb + (KT_),                &Bs[(Q_)*4096 + (w*32)*32]);      \
        lds16(gb + (KT_) + (size_t)16*K, &Bs[(Q_)*4096 + (w*32+16)*32]);   \
    } while (0)

    f32x4 acc[4][4] = {};
    const int NT = K >> 5;

    GSTAGE(0, 0);
    GSTAGE(1, 32);
    asm volatile("s_waitcnt vmcnt(4)" ::: "memory");
    __builtin_amdgcn_s_barrier();

    for (int t = 0; t < NT; ++t) {
        const int q = t & 3;
        if (t + 2 < NT) GSTAGE((t+2)&3, (t+2)*32);
        bf16x8 af[4], bfr[4];
        #pragma unroll
        for (int i = 0; i < 4; i++) {
            af[i]  = *(const bf16x8*)&As[q*4096 + (wr + i*16 + l15)*32 + l4*8];
            bfr[i] = *(const bf16x8*)&Bs[q*4096 + (wc + i*16 + l15)*32 + l4*8];
        }
        __builtin_amdgcn_s_setprio(1);
        #pragma unroll
        for (int i = 0; i < 4; i++)
            #pragma unroll
            for (int j = 0; j < 4; j++)
                acc[i][j] = __builtin_amdgcn_mfma_f32_16x16x32_bf16(af[i], bfr[j], acc[i][j], 0, 0, 0);
        __builtin_amdgcn_s_setprio(0);
        if (t + 2 < NT) {
            asm volatile("s_waitcnt vmcnt(4)" ::: "memory");
            __builtin_amdgcn_s_barrier();
        } else if (t + 1 < NT) {
            asm volatile("s_waitcnt vmcnt(0)" ::: "memory");
            __builtin_amdgcn_s_barrier();
        }
    }
#undef GSTAGE

    // ---- epilogue: bias-add, stage C (f32, XOR-swizzled cols) into LDS ----
    __syncthreads();                       // all waves done with As/Bs
    float* Ct = (float*)smem;              // 128*128*4 = 64 KB

    #pragma unroll
    for (int i = 0; i < 4; i++) {
        #pragma unroll
        for (int j = 0; j < 4; j++) {
            const int col = wc + j*16 + l15;
            const float bvv = bi[hd*128 + col];
            #pragma unroll
            for (int r = 0; r < 4; r++) {
                const int row = wr + i*16 + l4*4 + r;
                Ct[row*128 + (col ^ (row & 31))] = acc[i][j][r] + bvv;
            }
        }
    }
    __syncthreads();

    const int grow0 = bm*128;
    const int bb    = grow0 >> 11;         // batch index (tile within one batch)
    const int s0    = grow0 & (SEQ-1);

    if (mat < 2) {
        // RoPE + bf16 write, row-major
        __hip_bfloat16* Out = (mat==0) ? Qp : Kp;
        #pragma unroll
        for (int p = 0; p < 16; p++) {
            const int rl = p*8 + (tid>>5);
            const int c4 = (tid&31)*4;
            const int kx = rl & 31;
            const float* tc = tab + (size_t)(s0 + rl)*256;
            float o[4];
            #pragma unroll
            for (int i2 = 0; i2 < 4; i2++) {
                const int d  = c4 + i2;
                const float x  = Ct[rl*128 + (d ^ kx)];
                const int   pd = (d < 64) ? (2*d + 1) : (2*d - 128);
                const float xp = Ct[rl*128 + (pd ^ kx)];
                const float cs = tc[d], sn = tc[128 + d];
                o[i2] = (d < 64) ? (x*cs - xp*sn) : (x*cs + xp*sn);
            }
            ushort4 pkd;
            pkd.x = bfu(o[0]); pkd.y = bfu(o[1]); pkd.z = bfu(o[2]); pkd.w = bfu(o[3]);
            *(ushort4*)(Out + (size_t)(grow0 + rl)*D_MODEL + hd*HD + c4) = pkd;
        }
    } else {
        // transposed V write: Vt[(bb*16+hd)*128 + d][s0 + s]
        unsigned short* vt = (unsigned short*)Vt;
        #pragma unroll
        for (int p = 0; p < 16; p++) {
            const int d  = p*8 + (tid>>5);
            const int s4 = (tid&31)*4;
            float o[4];
            #pragma unroll
            for (int i2 = 0; i2 < 4; i2++) {
                const int sr = s4 + i2;
                o[i2] = Ct[sr*128 + (d ^ (sr & 31))];
            }
            ushort4 pkd;
            pkd.x = bfu(o[0]); pkd.y = bfu(o[1]); pkd.z = bfu(o[2]); pkd.w = bfu(o[3]);
            *(ushort4*)(vt + ((size_t)(bb*16 + hd)*HD + d)*SEQ + s0 + s4) = pkd;
        }
    }
}

// ---------------- O-projection GEMM (f32 out + bias), 4-deep pipeline -------
__global__ __launch_bounds__(256, 2) void gemm_bt_bias_f32(
    const __hip_bfloat16* __restrict__ A,
    const __hip_bfloat16* __restrict__ W,
    const float* __restrict__ bias,
    float* __restrict__ C,
    const int M, const int N, const int K)
{
    __shared__ __hip_bfloat16 As[4][128*32];
    __shared__ __hip_bfloat16 Bs[4][128*32];
    const int nb   = N >> 7;
    const int bm   = blockIdx.x / nb;
    const int bn   = blockIdx.x % nb;
    const int tid  = threadIdx.x;
    const int lane = tid & 63;
    const int w    = tid >> 6;
    const int wr   = (w >> 1) * 64;
    const int wc   = (w & 1) * 64;
    const int l15  = lane & 15, l4 = lane >> 4;

    const int srow = w*32 + (lane>>2);
    const __hip_bfloat16* ga = A + (size_t)(bm*128 + srow)*K + (lane&3)*8;
    const __hip_bfloat16* gb = W + (size_t)(bn*128 + srow)*K + (lane&3)*8;

#define GSTAGE(Q_, KT_) do {                                          \
        lds16(ga + (KT_),                &As[Q_][(w*32)*32]);         \
        lds16(ga + (KT_) + (size_t)16*K, &As[Q_][(w*32+16)*32]);      \
        lds16(gb + (KT_),                &Bs[Q_][(w*32)*32]);         \
        lds16(gb + (KT_) + (size_t)16*K, &Bs[Q_][(w*32+16)*32]);      \
    } while (0)

    f32x4 acc[4][4] = {};
    const int NT = K >> 5;

    GSTAGE(0, 0);
    GSTAGE(1, 32);
    asm volatile("s_waitcnt vmcnt(4)" ::: "memory");
    __builtin_amdgcn_s_barrier();

    for (int t = 0; t < NT; ++t) {
        const int q = t & 3;
        if (t + 2 < NT) GSTAGE((t+2)&3, (t+2)*32);
        bf16x8 af[4], bfr[4];
        #pragma unroll
        for (int i = 0; i < 4; i++) {
            af[i]  = *(const bf16x8*)&As[q][(wr + i*16 + l15)*32 + l4*8];
            bfr[i] = *(const bf16x8*)&Bs[q][(wc + i*16 + l15)*32 + l4*8];
        }
        __builtin_amdgcn_s_setprio(1);
        #pragma unroll
        for (int i = 0; i < 4; i++)
            #pragma unroll
            for (int j = 0; j < 4; j++)
                acc[i][j] = __builtin_amdgcn_mfma_f32_16x16x32_bf16(af[i], bfr[j], acc[i][j], 0, 0, 0);
        __builtin_amdgcn_s_setprio(0);
        if (t + 2 < NT) {
            asm volatile("s_waitcnt vmcnt(4)" ::: "memory");
            __builtin_amdgcn_s_barrier();
        } else if (t + 1 < NT) {
            asm volatile("s_waitcnt vmcnt(0)" ::: "memory");
            __builtin_amdgcn_s_barrier();
        }
    }
#undef GSTAGE

    float bv[4];
    #pragma unroll
    for (int j = 0; j < 4; j++)
        bv[j] = bias[bn*128 + wc + j*16 + l15];
    #pragma unroll
    for (int i = 0; i < 4; i++) {
        #pragma unroll
        for (int j = 0; j < 4; j++) {
            const int col = bn*128 + wc + j*16 + l15;
            #pragma unroll
            for (int r = 0; r < 4; r++) {
                const int row = bm*128 + wr + i*16 + l4*4 + r;
                C[(size_t)row*N + col] = acc[i][j][r] + bv[j];
            }
        }
    }
}

// ---------------------------------------------------------------------------
// Flash attention (r3 variant, best measured): 4 waves, block owns 128 q rows,
// KV chunk 64, K[64][128]+Vt[128][64] LDS dbuf, swapped QK^T, in-reg softmax.
// ---------------------------------------------------------------------------
__global__ __launch_bounds__(256, 2) void flash_attn(
    const __hip_bfloat16* __restrict__ Qg,
    const __hip_bfloat16* __restrict__ Kg,
    const __hip_bfloat16* __restrict__ Vtg,
    __hip_bfloat16* __restrict__ ctx)
{
    __shared__ __hip_bfloat16 Ks[2][64*128];
    __shared__ __hip_bfloat16 Vs[2][128*64];

    const int tid  = threadIdx.x;
    const int w    = tid >> 6;
    const int lane = tid & 63;
    const int l31  = lane & 31;
    const int hi   = lane >> 5;
    const bool hib = (hi != 0);

    const int bid0 = blockIdx.x;                     // 512 blocks
    const int bid  = (bid0 & 7)*64 + (bid0 >> 3);    // XCD-aware swizzle
    const int bh   = bid >> 4;
    const int qt   = bid & 15;
    const int bi   = bh >> 4, h = bh & 15;
    const int q0   = qt * 128;

    const float SC = 0.08838834764831845f;   // 1/sqrt(128)

    bf16x8 aq[8];
    {
        const __hip_bfloat16* qp =
            Qg + (size_t)(bi*SEQ + q0 + w*32 + l31)*D_MODEL + h*HD + hi*8;
        #pragma unroll
        for (int ds = 0; ds < 8; ds++) aq[ds] = *(const bf16x8*)(qp + ds*16);
    }

#define STAGE(NB, KV) do {                                                              \
        _Pragma("unroll")                                                               \
        for (int i_ = 0; i_ < 4; i_++) {                                                \
            const int kr_ = w*16 + i_*4 + (lane>>4);                                    \
            lds16(Kg + (size_t)(bi*SEQ + (KV) + kr_)*D_MODEL + h*HD                     \
                      + (((lane&15) ^ (kr_&15))*8),                                     \
                  &Ks[NB][(w*16 + i_*4)*128]);                                          \
        }                                                                               \
        _Pragma("unroll")                                                               \
        for (int i_ = 0; i_ < 4; i_++) {                                                \
            const int vr_ = w*32 + i_*8 + (lane>>3);                                    \
            lds16(Vtg + ((size_t)bh*HD + vr_)*SEQ + (KV)                                \
                      + (((lane&7) ^ (lane>>3))*8),                                     \
                  &Vs[NB][(w*32 + i_*8)*64]);                                           \
        }                                                                               \
    } while (0)

    f32x16 o0 = {}, o1 = {}, o2 = {}, o3 = {};
    float m_run = -1e30f, l_run = 0.0f;

    STAGE(0, 0);

    for (int t = 0; t < SEQ/64; t++) {
        const int cb = t & 1;
        __syncthreads();
        if (t < SEQ/64 - 1) STAGE(cb^1, (t+1)*64);

        f32x16 p0 = {}, p1 = {};
        #pragma unroll
        for (int ds = 0; ds < 8; ds++) {
            const int sl = ((ds*2 + hi) ^ (lane&15)) * 8;
            const bf16x8 k0 = *(const bf16x8*)&Ks[cb][l31*128 + sl];
            const bf16x8 k1 = *(const bf16x8*)&Ks[cb][(32 + l31)*128 + sl];
            p0 = __builtin_amdgcn_mfma_f32_32x32x16_bf16(k0, aq[ds], p0, 0, 0, 0);
            p1 = __builtin_amdgcn_mfma_f32_32x32x16_bf16(k1, aq[ds], p1, 0, 0, 0);
        }

        float pm = fmaxf(p0[0], p1[0]);
        #pragma unroll
        for (int r = 1; r < 16; r++) pm = fmaxf(pm, fmaxf(p0[r], p1[r]));
        pm = fmaxf(pm, __shfl_xor(pm, 32));

        if (!__all(pm <= m_run + 90.509667f)) {
            const float mnew = fmaxf(m_run, pm);
            const float al = __expf((m_run - mnew) * SC);
            l_run *= al;
            m_run = mnew;
            float alr[16];
            #pragma unroll
            for (int r = 0; r < 16; r++)
                alr[r] = __shfl(al, (r&3) + 8*(r>>2) + (hib ? 4 : 0));
            #pragma unroll
            for (int r = 0; r < 16; r++) {
                o0[r] *= alr[r]; o1[r] *= alr[r]; o2[r] *= alr[r]; o3[r] *= alr[r];
            }
        }

        #pragma unroll
        for (int r = 0; r < 16; r++) {
            p0[r] = __expf((p0[r] - m_run) * SC);
            p1[r] = __expf((p1[r] - m_run) * SC);
        }
        float rs = 0.0f;
        #pragma unroll
        for (int r = 0; r < 16; r++) rs += p0[r] + p1[r];
        rs += __shfl_xor(rs, 32);
        l_run += rs;

#define PV_STEP(PF, KS) do {                                                            \
            const unsigned int A0_ = pk2(PF[8*((KS)&1)+0], PF[8*((KS)&1)+1]);           \
            const unsigned int A1_ = pk2(PF[8*((KS)&1)+2], PF[8*((KS)&1)+3]);           \
            const unsigned int B0_ = pk2(PF[8*((KS)&1)+4], PF[8*((KS)&1)+5]);           \
            const unsigned int B1_ = pk2(PF[8*((KS)&1)+6], PF[8*((KS)&1)+7]);           \
            const unsigned int s0_ = hib ? A0_ : B0_;                                   \
            const unsigned int s1_ = hib ? A1_ : B1_;                                   \
            const unsigned int r0_ = (unsigned int)__shfl_xor((int)s0_, 32);            \
            const unsigned int r1_ = (unsigned int)__shfl_xor((int)s1_, 32);            \
            u32x4 au_;                                                                  \
            au_.x = hib ? r0_ : A0_;  au_.y = hib ? r1_ : A1_;                          \
            au_.z = hib ? B0_ : r0_;  au_.w = hib ? B1_ : r1_;                          \
            const bf16x8 pa_ = *(const bf16x8*)&au_;                                    \
            const int ko_ = (((KS)*2 + hi) ^ (lane&7)) * 8;                             \
            o0 = __builtin_amdgcn_mfma_f32_32x32x16_bf16(pa_,                           \
                     *(const bf16x8*)&Vs[cb][(  0 + l31)*64 + ko_], o0, 0, 0, 0);       \
            o1 = __builtin_amdgcn_mfma_f32_32x32x16_bf16(pa_,                           \
                     *(const bf16x8*)&Vs[cb][( 32 + l31)*64 + ko_], o1, 0, 0, 0);       \
            o2 = __builtin_amdgcn_mfma_f32_32x32x16_bf16(pa_,                           \
                     *(const bf16x8*)&Vs[cb][( 64 + l31)*64 + ko_], o2, 0, 0, 0);       \
            o3 = __builtin_amdgcn_mfma_f32_32x32x16_bf16(pa_,                           \
                     *(const bf16x8*)&Vs[cb][( 96 + l31)*64 + ko_], o3, 0, 0, 0);       \
        } while (0)

        PV_STEP(p0, 0); PV_STEP(p0, 1); PV_STEP(p1, 2); PV_STEP(p1, 3);
#undef PV_STEP
    }

    const float inv = 1.0f / l_run;
    float invr[16];
    #pragma unroll
    for (int r = 0; r < 16; r++)
        invr[r] = __shfl(inv, (r&3) + 8*(r>>2) + (hib ? 4 : 0));

    #pragma unroll
    for (int r = 0; r < 16; r++) {
        const int qr = q0 + w*32 + (r&3) + 8*(r>>2) + (hib ? 4 : 0);
        __hip_bfloat16* cp = ctx + (size_t)(bi*SEQ + qr)*D_MODEL + h*HD + l31;
        cp[0]  = __float2bfloat16(o0[r] * invr[r]);
        cp[32] = __float2bfloat16(o1[r] * invr[r]);
        cp[64] = __float2bfloat16(o2[r] * invr[r]);
        cp[96] = __float2bfloat16(o3[r] * invr[r]);
    }
#undef STAGE
}

extern "C" void kernel_launch(void* const* d_in, const int* in_sizes, int n_in,
                              void* d_out, int out_size, void* d_ws, size_t ws_size,
                              hipStream_t stream)
{
    const float* query = (const float*)d_in[0];
    const float* key   = (const float*)d_in[1];
    const float* value = (const float*)d_in[2];
    const float* Wq    = (const float*)d_in[3];
    const float* bq    = (const float*)d_in[4];
    const float* Wk    = (const float*)d_in[5];
    const float* bk    = (const float*)d_in[6];
    const float* Wv    = (const float*)d_in[7];
    const float* bv    = (const float*)d_in[8];
    const float* Wo    = (const float*)d_in[9];
    const float* bo    = (const float*)d_in[10];
    float* out = (float*)d_out;

    char* ws = (char*)d_ws;
    const size_t MB = 1024*1024;
    __hip_bfloat16* qb  = (__hip_bfloat16*)(ws);
    __hip_bfloat16* kbuf= (__hip_bfloat16*)(ws + 16*MB);
    __hip_bfloat16* vbuf= (__hip_bfloat16*)(ws + 32*MB);
    __hip_bfloat16* Qp  = (__hip_bfloat16*)(ws + 48*MB);
    __hip_bfloat16* Kp  = (__hip_bfloat16*)(ws + 64*MB);
    __hip_bfloat16* Vt  = (__hip_bfloat16*)(ws + 80*MB);
    __hip_bfloat16* ctx = (__hip_bfloat16*)(ws + 96*MB);
    __hip_bfloat16* Wqb = (__hip_bfloat16*)(ws + 112*MB);
    __hip_bfloat16* Wkb = (__hip_bfloat16*)(ws + 120*MB);
    __hip_bfloat16* Wvb = (__hip_bfloat16*)(ws + 128*MB);
    __hip_bfloat16* Wob = (__hip_bfloat16*)(ws + 136*MB);
    float*          tab = (float*)         (ws + 144*MB);

    cvt_all<<<40960, 256, 0, stream>>>(query, key, value, Wq, Wk, Wv, Wo,
        (unsigned short*)qb, (unsigned short*)kbuf, (unsigned short*)vbuf,
        (unsigned short*)Wqb, (unsigned short*)Wkb, (unsigned short*)Wvb,
        (unsigned short*)Wob);

    rope_table<<<SEQ*HD/256, 256, 0, stream>>>(tab);

    gemm_qkv_fused<<<(MROWS/128)*48, 256, 0, stream>>>(
        qb, kbuf, vbuf, Wqb, Wkb, Wvb, bq, bk, bv, tab, Qp, Kp, Vt);

    flash_attn<<<BATCH*NH*(SEQ/128), 256, 0, stream>>>(Qp, Kp, Vt, ctx);

    gemm_bt_bias_f32<<<(MROWS/128)*(D_MODEL/128), 256, 0, stream>>>(
        ctx, Wob, bo, out, MROWS, D_MODEL, D_MODEL);
}